// Round 4
// baseline (178.207 us; speedup 1.0000x reference)
//
#include <hip/hip_runtime.h>
#include <hip/hip_bf16.h>

#define HW    4096
#define CIN   256
#define NB    8
#define T_FR  8
#define CTX_ELEMS (NB * 256 * 512)      // 1,048,576 = 2^20

typedef __attribute__((ext_vector_type(8))) short short8;
typedef __attribute__((ext_vector_type(4))) float f32x4;

__device__ __forceinline__ unsigned short f2bf(float f) {
  union { float f; unsigned int u; } v; v.f = f;
  unsigned int r = v.u + 0x7fffu + ((v.u >> 16) & 1u);   // RNE
  return (unsigned short)(r >> 16);
}
__device__ __forceinline__ float bf2f(unsigned short u) {
  union { unsigned int u; float f; } v; v.u = ((unsigned int)u) << 16;
  return v.f;
}

// ---------------------------------------------------------------------------
// k_feat: feat[b,f,p] = sum_c x[b*T, c, p] * Wf[f,c] + bias  -> bf16 ws
// A = x^T (per-lane direct global column-gather, f32->bf16 cvt),
// B = Wf tile (n = 128 f) staged bf16 in LDS (264-short padded rows).
// ---------------------------------------------------------------------------
#define LROW 264
__global__ __launch_bounds__(256) void k_feat(
    const float* __restrict__ x, const float* __restrict__ Wf,
    const float* __restrict__ bfeat, unsigned short* __restrict__ featbf) {
  const int p0  = blockIdx.x * 128;
  const int f0t = blockIdx.y * 128;
  const int b   = blockIdx.z;
  __shared__ unsigned short Wsh[128 * LROW];   // 67.6 KB
  const int tid = threadIdx.x, lane = tid & 63, wave = tid >> 6;
  {
    const int row = tid >> 1, seg = tid & 1;
    const float* src = Wf + (size_t)(f0t + row) * CIN + seg * 128;
    unsigned short* dst = &Wsh[row * LROW + seg * 128];
#pragma unroll
    for (int i = 0; i < 16; ++i) {
      float4 va = *(const float4*)(src + i * 8);
      float4 vb = *(const float4*)(src + i * 8 + 4);
      short8 w;
      w[0] = (short)f2bf(va.x); w[1] = (short)f2bf(va.y);
      w[2] = (short)f2bf(va.z); w[3] = (short)f2bf(va.w);
      w[4] = (short)f2bf(vb.x); w[5] = (short)f2bf(vb.y);
      w[6] = (short)f2bf(vb.z); w[7] = (short)f2bf(vb.w);
      *(short8*)(dst + i * 8) = w;
    }
  }
  __syncthreads();
  const int r = lane & 15, kg = lane >> 4;
  const int pw = p0 + wave * 32;
  const float* xs = x + (size_t)(b * T_FR) * CIN * HW;   // frame 0 of clip b
  f32x4 acc[2][8] = {};
  for (int ks = 0; ks < 8; ++ks) {
    short8 afr[2];
#pragma unroll
    for (int mi = 0; mi < 2; ++mi) {
      const float* col = xs + (size_t)(ks * 32 + kg * 8) * HW + pw + mi * 16 + r;
#pragma unroll
      for (int j = 0; j < 8; ++j) afr[mi][j] = (short)f2bf(col[(size_t)j * HW]);
    }
    short8 bfr[8];
#pragma unroll
    for (int nj = 0; nj < 8; ++nj)
      bfr[nj] = *(const short8*)&Wsh[(nj * 16 + r) * LROW + ks * 32 + kg * 8];
#pragma unroll
    for (int mi = 0; mi < 2; ++mi)
#pragma unroll
      for (int nj = 0; nj < 8; ++nj)
        acc[mi][nj] = __builtin_amdgcn_mfma_f32_16x16x32_bf16(afr[mi], bfr[nj], acc[mi][nj], 0, 0, 0);
  }
#pragma unroll
  for (int nj = 0; nj < 8; ++nj) {
    const int f = f0t + nj * 16 + r;
    const float bias = bfeat[f];
#pragma unroll
    for (int mi = 0; mi < 2; ++mi) {
      ushort4 u;
      u.x = f2bf(acc[mi][nj][0] + bias);
      u.y = f2bf(acc[mi][nj][1] + bias);
      u.z = f2bf(acc[mi][nj][2] + bias);
      u.w = f2bf(acc[mi][nj][3] + bias);
      *(ushort4*)&featbf[(size_t)(b * 256 + f) * HW + pw + mi * 16 + kg * 4] = u;
    }
  }
}

// ---------------------------------------------------------------------------
// k_att: logits = Wa @ x[s] + bias; e = exp(logit); store e (bf16) to ws;
// write per-pblock row-sum partials (deterministic, no atomics, no memset).
// ---------------------------------------------------------------------------
__global__ __launch_bounds__(256) void k_att(
    const float* __restrict__ x, const float* __restrict__ Wa,
    const float* __restrict__ batt, unsigned short* __restrict__ attbf,
    float* __restrict__ rsum_part) {
  const int p0 = blockIdx.x * 128;
  const int s  = blockIdx.y;
  __shared__ unsigned short Wsh[64 * LROW];    // 33.8 KB
  __shared__ float wsum[4][64];
  const int tid = threadIdx.x, lane = tid & 63, wave = tid >> 6;
  {
    const int row = tid >> 2, seg = tid & 3;
    const float* src = Wa + (size_t)row * CIN + seg * 64;
    unsigned short* dst = &Wsh[row * LROW + seg * 64];
#pragma unroll
    for (int i = 0; i < 8; ++i) {
      float4 va = *(const float4*)(src + i * 8);
      float4 vb = *(const float4*)(src + i * 8 + 4);
      short8 w;
      w[0] = (short)f2bf(va.x); w[1] = (short)f2bf(va.y);
      w[2] = (short)f2bf(va.z); w[3] = (short)f2bf(va.w);
      w[4] = (short)f2bf(vb.x); w[5] = (short)f2bf(vb.y);
      w[6] = (short)f2bf(vb.z); w[7] = (short)f2bf(vb.w);
      *(short8*)(dst + i * 8) = w;
    }
  }
  __syncthreads();
  const int r = lane & 15, kg = lane >> 4;
  const int pw = p0 + wave * 32;
  const float* xs = x + (size_t)s * CIN * HW;
  f32x4 acc[2][4] = {};
  for (int ks = 0; ks < 8; ++ks) {
    short8 afr[2];
#pragma unroll
    for (int mi = 0; mi < 2; ++mi) {
      const float* col = xs + (size_t)(ks * 32 + kg * 8) * HW + pw + mi * 16 + r;
#pragma unroll
      for (int j = 0; j < 8; ++j) afr[mi][j] = (short)f2bf(col[(size_t)j * HW]);
    }
    short8 bfr[4];
#pragma unroll
    for (int nj = 0; nj < 4; ++nj)
      bfr[nj] = *(const short8*)&Wsh[(nj * 16 + r) * LROW + ks * 32 + kg * 8];
#pragma unroll
    for (int mi = 0; mi < 2; ++mi)
#pragma unroll
      for (int nj = 0; nj < 4; ++nj)
        acc[mi][nj] = __builtin_amdgcn_mfma_f32_16x16x32_bf16(afr[mi], bfr[nj], acc[mi][nj], 0, 0, 0);
  }
  const int b = s >> 3, t = s & 7;
  float rowpart[4];
#pragma unroll
  for (int nj = 0; nj < 4; ++nj) {
    const int a = nj * 16 + r;
    const float bias = batt[a];
    float sp = 0.f;
#pragma unroll
    for (int mi = 0; mi < 2; ++mi) {
      float e0 = __expf(acc[mi][nj][0] + bias);
      float e1 = __expf(acc[mi][nj][1] + bias);
      float e2 = __expf(acc[mi][nj][2] + bias);
      float e3 = __expf(acc[mi][nj][3] + bias);
      sp += e0 + e1 + e2 + e3;
      ushort4 u;
      u.x = f2bf(e0); u.y = f2bf(e1); u.z = f2bf(e2); u.w = f2bf(e3);
      *(ushort4*)&attbf[(size_t)(b * 512 + t * 64 + a) * HW + pw + mi * 16 + kg * 4] = u;
    }
    sp += __shfl_xor(sp, 16);
    sp += __shfl_xor(sp, 32);
    rowpart[nj] = sp;
  }
  if (lane < 16) {
#pragma unroll
    for (int nj = 0; nj < 4; ++nj) wsum[wave][nj * 16 + r] = rowpart[nj];
  }
  __syncthreads();
  if (tid < 64) {
    float tot = wsum[0][tid] + wsum[1][tid] + wsum[2][tid] + wsum[3][tid];
    rsum_part[(size_t)blockIdx.x * 4096 + b * 512 + t * 64 + tid] = tot;
  }
}

// ---------------------------------------------------------------------------
// k_rsum: rsum[row] = sum_{pblk<32} rsum_part[pblk][row].  16 blocks x 256.
// ---------------------------------------------------------------------------
__global__ __launch_bounds__(256) void k_rsum(
    const float* __restrict__ rsum_part, float* __restrict__ rsum) {
  const int row = blockIdx.x * 256 + threadIdx.x;
  float s = 0.f;
#pragma unroll
  for (int j = 0; j < 32; ++j) s += rsum_part[(size_t)j * 4096 + row];
  rsum[row] = s;
}

// ---------------------------------------------------------------------------
// k_ctx: split-K(4) partial GEMM + fused attn output.
//   partial[q][b][f][a] = sum_{p in q-quarter} feat[b,f,p]*e[b,a,p]
//   ftile==0 blocks additionally write attn[b, a0+row, q-cols] = e * (1/rsum)
// A = featbf direct global (K-contig), B = attbf staged in LDS.
// Block: 128f x 64a, K = 1024.  Grid (8 atile, 2 ftile, 32 = b*4+q).
// ---------------------------------------------------------------------------
__global__ __launch_bounds__(256) void k_ctx(
    const unsigned short* __restrict__ featbf,
    const unsigned short* __restrict__ attbf,
    const float* __restrict__ rsum,
    float* __restrict__ partial,
    float* __restrict__ attn) {
  const int a0 = blockIdx.x * 64;
  const int ft = blockIdx.y;
  const int b  = blockIdx.z >> 2;
  const int q  = blockIdx.z & 3;
  __shared__ unsigned short Bsh[64 * LROW];    // 33.8 KB
  const int tid = threadIdx.x, lane = tid & 63, wave = tid >> 6;
  const int r = lane & 15, kg = lane >> 4;
  const int fbase = ft * 128 + wave * 32;
  const int brow = tid >> 2;            // 0..63  (a-row within tile)
  const int bseg = (tid & 3) * 64;      // col segment within 256-chunk
  const unsigned short* Arow = featbf + (size_t)(b * 256 + fbase + r) * HW + q * 1024 + kg * 8;
  const unsigned short* Bsrc = attbf + (size_t)(b * 512 + a0 + brow) * HW + q * 1024 + bseg;
  unsigned short* Bdst = &Bsh[brow * LROW + bseg];
  float* attn_row = attn + (size_t)(b * 512 + a0 + brow) * HW + q * 1024 + bseg;
  const bool wr = (ft == 0);
  const float inv = 1.0f / rsum[b * 512 + a0 + brow];
  f32x4 acc[2][4] = {};
  for (int ch = 0; ch < 4; ++ch) {      // 4 x 256-col chunks of this K-quarter
    __syncthreads();
#pragma unroll
    for (int i = 0; i < 8; ++i) {
      short8 v = *(const short8*)(Bsrc + ch * 256 + i * 8);
      *(short8*)(Bdst + i * 8) = v;
      if (wr) {
        float4 o0, o1;
        o0.x = bf2f((unsigned short)v[0]) * inv;
        o0.y = bf2f((unsigned short)v[1]) * inv;
        o0.z = bf2f((unsigned short)v[2]) * inv;
        o0.w = bf2f((unsigned short)v[3]) * inv;
        o1.x = bf2f((unsigned short)v[4]) * inv;
        o1.y = bf2f((unsigned short)v[5]) * inv;
        o1.z = bf2f((unsigned short)v[6]) * inv;
        o1.w = bf2f((unsigned short)v[7]) * inv;
        *(float4*)(attn_row + ch * 256 + i * 8) = o0;
        *(float4*)(attn_row + ch * 256 + i * 8 + 4) = o1;
      }
    }
    __syncthreads();
#pragma unroll
    for (int ks = 0; ks < 8; ++ks) {
      short8 afr[2];
      afr[0] = *(const short8*)(Arow + ch * 256 + ks * 32);
      afr[1] = *(const short8*)(Arow + ch * 256 + ks * 32 + (size_t)16 * HW);
      short8 bfr[4];
#pragma unroll
      for (int nj = 0; nj < 4; ++nj)
        bfr[nj] = *(const short8*)&Bsh[(nj * 16 + r) * LROW + ks * 32 + kg * 8];
#pragma unroll
      for (int mi = 0; mi < 2; ++mi)
#pragma unroll
        for (int nj = 0; nj < 4; ++nj)
          acc[mi][nj] = __builtin_amdgcn_mfma_f32_16x16x32_bf16(afr[mi], bfr[nj], acc[mi][nj], 0, 0, 0);
    }
  }
  const size_t base = ((size_t)q << 20) + (size_t)b * (256 * 512);
#pragma unroll
  for (int mi = 0; mi < 2; ++mi)
#pragma unroll
    for (int nj = 0; nj < 4; ++nj)
#pragma unroll
      for (int reg = 0; reg < 4; ++reg) {
        const int f = fbase + mi * 16 + kg * 4 + reg;
        const int a = a0 + nj * 16 + r;
        partial[base + (size_t)f * 512 + a] = acc[mi][nj][reg];
      }
}

// ---------------------------------------------------------------------------
// k_ctxred: ctx[idx] = (sum_{q<4} partial[q][idx]) / rsum[row_a]
// ---------------------------------------------------------------------------
__global__ __launch_bounds__(256) void k_ctxred(
    const float* __restrict__ partial, const float* __restrict__ rsum,
    float* __restrict__ ctx) {
  const int idx = blockIdx.x * 256 + threadIdx.x;
  const int a = idx & 511, b = idx >> 17;
  float s = partial[idx] + partial[(1 << 20) + idx] +
            partial[(2 << 20) + idx] + partial[(3 << 20) + idx];
  ctx[idx] = s / rsum[b * 512 + a];
}

// ---------------------------------------------------------------------------
extern "C" void kernel_launch(void* const* d_in, const int* in_sizes, int n_in,
                              void* d_out, int out_size, void* d_ws, size_t ws_size,
                              hipStream_t stream) {
  const float* x     = (const float*)d_in[0];
  const float* Wf    = (const float*)d_in[1];
  const float* bfeat = (const float*)d_in[2];
  const float* Wa    = (const float*)d_in[3];
  const float* ba    = (const float*)d_in[4];
  float* ctx  = (float*)d_out;
  float* attn = ctx + CTX_ELEMS;

  unsigned short* featbf = (unsigned short*)d_ws;                 // 16.8 MB
  unsigned short* attbf  = featbf + (size_t)NB * 256 * HW;        // 33.6 MB
  float* rsum_part = (float*)(attbf + (size_t)4096 * HW);         // 512 KB
  float* rsum = rsum_part + 32 * 4096;                            // 16 KB
  float* partial = rsum + 4096;                                   // 16.8 MB

  k_feat<<<dim3(32, 2, NB), 256, 0, stream>>>(x, Wf, bfeat, featbf);
  k_att<<<dim3(32, 64), 256, 0, stream>>>(x, Wa, ba, attbf, rsum_part);
  k_rsum<<<16, 256, 0, stream>>>(rsum_part, rsum);
  k_ctx<<<dim3(8, 2, 32), 256, 0, stream>>>(featbf, attbf, rsum, partial, attn);
  k_ctxred<<<4096, 256, 0, stream>>>(partial, rsum, ctx);
}

// Round 5
// 173.934 us; speedup vs baseline: 1.0246x; 1.0246x over previous
//
#include <hip/hip_runtime.h>
#include <hip/hip_bf16.h>

#define HW    4096
#define CIN   256
#define NB    8
#define T_FR  8
#define CTX_ELEMS (NB * 256 * 512)      // 1,048,576 = 2^20

typedef __attribute__((ext_vector_type(8))) short short8;
typedef __attribute__((ext_vector_type(4))) float f32x4;

__device__ __forceinline__ unsigned short f2bf(float f) {
  union { float f; unsigned int u; } v; v.f = f;
  unsigned int r = v.u + 0x7fffu + ((v.u >> 16) & 1u);   // RNE
  return (unsigned short)(r >> 16);
}
__device__ __forceinline__ float bf2f(unsigned short u) {
  union { unsigned int u; float f; } v; v.u = ((unsigned int)u) << 16;
  return v.f;
}

// ---------------------------------------------------------------------------
// k_feat: feat[b,f,p] = sum_c x[b*T, c, p] * Wf[f,c] + bias  -> bf16 ws
// A = x^T (per-lane direct global column-gather, f32->bf16 cvt),
// B = Wf tile (n = 128 f) staged bf16 in LDS (264-short padded rows).
// ---------------------------------------------------------------------------
#define LROW 264
__global__ __launch_bounds__(256) void k_feat(
    const float* __restrict__ x, const float* __restrict__ Wf,
    const float* __restrict__ bfeat, unsigned short* __restrict__ featbf) {
  const int p0  = blockIdx.x * 128;
  const int f0t = blockIdx.y * 128;
  const int b   = blockIdx.z;
  __shared__ unsigned short Wsh[128 * LROW];   // 67.6 KB
  const int tid = threadIdx.x, lane = tid & 63, wave = tid >> 6;
  {
    const int row = tid >> 1, seg = tid & 1;
    const float* src = Wf + (size_t)(f0t + row) * CIN + seg * 128;
    unsigned short* dst = &Wsh[row * LROW + seg * 128];
#pragma unroll
    for (int i = 0; i < 16; ++i) {
      float4 va = *(const float4*)(src + i * 8);
      float4 vb = *(const float4*)(src + i * 8 + 4);
      short8 w;
      w[0] = (short)f2bf(va.x); w[1] = (short)f2bf(va.y);
      w[2] = (short)f2bf(va.z); w[3] = (short)f2bf(va.w);
      w[4] = (short)f2bf(vb.x); w[5] = (short)f2bf(vb.y);
      w[6] = (short)f2bf(vb.z); w[7] = (short)f2bf(vb.w);
      *(short8*)(dst + i * 8) = w;
    }
  }
  __syncthreads();
  const int r = lane & 15, kg = lane >> 4;
  const int pw = p0 + wave * 32;
  const float* xs = x + (size_t)(b * T_FR) * CIN * HW;   // frame 0 of clip b
  f32x4 acc[2][8] = {};
  for (int ks = 0; ks < 8; ++ks) {
    short8 afr[2];
#pragma unroll
    for (int mi = 0; mi < 2; ++mi) {
      const float* col = xs + (size_t)(ks * 32 + kg * 8) * HW + pw + mi * 16 + r;
#pragma unroll
      for (int j = 0; j < 8; ++j) afr[mi][j] = (short)f2bf(col[(size_t)j * HW]);
    }
    short8 bfr[8];
#pragma unroll
    for (int nj = 0; nj < 8; ++nj)
      bfr[nj] = *(const short8*)&Wsh[(nj * 16 + r) * LROW + ks * 32 + kg * 8];
#pragma unroll
    for (int mi = 0; mi < 2; ++mi)
#pragma unroll
      for (int nj = 0; nj < 8; ++nj)
        acc[mi][nj] = __builtin_amdgcn_mfma_f32_16x16x32_bf16(afr[mi], bfr[nj], acc[mi][nj], 0, 0, 0);
  }
#pragma unroll
  for (int nj = 0; nj < 8; ++nj) {
    const int f = f0t + nj * 16 + r;
    const float bias = bfeat[f];
#pragma unroll
    for (int mi = 0; mi < 2; ++mi) {
      ushort4 u;
      u.x = f2bf(acc[mi][nj][0] + bias);
      u.y = f2bf(acc[mi][nj][1] + bias);
      u.z = f2bf(acc[mi][nj][2] + bias);
      u.w = f2bf(acc[mi][nj][3] + bias);
      *(ushort4*)&featbf[(size_t)(b * 256 + f) * HW + pw + mi * 16 + kg * 4] = u;
    }
  }
}

// ---------------------------------------------------------------------------
// k_att: logits = Wa @ x[s] + bias; e = exp(logit); store e (bf16) to ws;
// write per-pblock row-sum partials (deterministic, no atomics, no memset).
// ---------------------------------------------------------------------------
__global__ __launch_bounds__(256) void k_att(
    const float* __restrict__ x, const float* __restrict__ Wa,
    const float* __restrict__ batt, unsigned short* __restrict__ attbf,
    float* __restrict__ rsum_part) {
  const int p0 = blockIdx.x * 128;
  const int s  = blockIdx.y;
  __shared__ unsigned short Wsh[64 * LROW];    // 33.8 KB
  __shared__ float wsum[4][64];
  const int tid = threadIdx.x, lane = tid & 63, wave = tid >> 6;
  {
    const int row = tid >> 2, seg = tid & 3;
    const float* src = Wa + (size_t)row * CIN + seg * 64;
    unsigned short* dst = &Wsh[row * LROW + seg * 64];
#pragma unroll
    for (int i = 0; i < 8; ++i) {
      float4 va = *(const float4*)(src + i * 8);
      float4 vb = *(const float4*)(src + i * 8 + 4);
      short8 w;
      w[0] = (short)f2bf(va.x); w[1] = (short)f2bf(va.y);
      w[2] = (short)f2bf(va.z); w[3] = (short)f2bf(va.w);
      w[4] = (short)f2bf(vb.x); w[5] = (short)f2bf(vb.y);
      w[6] = (short)f2bf(vb.z); w[7] = (short)f2bf(vb.w);
      *(short8*)(dst + i * 8) = w;
    }
  }
  __syncthreads();
  const int r = lane & 15, kg = lane >> 4;
  const int pw = p0 + wave * 32;
  const float* xs = x + (size_t)s * CIN * HW;
  f32x4 acc[2][4] = {};
  for (int ks = 0; ks < 8; ++ks) {
    short8 afr[2];
#pragma unroll
    for (int mi = 0; mi < 2; ++mi) {
      const float* col = xs + (size_t)(ks * 32 + kg * 8) * HW + pw + mi * 16 + r;
#pragma unroll
      for (int j = 0; j < 8; ++j) afr[mi][j] = (short)f2bf(col[(size_t)j * HW]);
    }
    short8 bfr[4];
#pragma unroll
    for (int nj = 0; nj < 4; ++nj)
      bfr[nj] = *(const short8*)&Wsh[(nj * 16 + r) * LROW + ks * 32 + kg * 8];
#pragma unroll
    for (int mi = 0; mi < 2; ++mi)
#pragma unroll
      for (int nj = 0; nj < 4; ++nj)
        acc[mi][nj] = __builtin_amdgcn_mfma_f32_16x16x32_bf16(afr[mi], bfr[nj], acc[mi][nj], 0, 0, 0);
  }
  const int b = s >> 3, t = s & 7;
  float rowpart[4];
#pragma unroll
  for (int nj = 0; nj < 4; ++nj) {
    const int a = nj * 16 + r;
    const float bias = batt[a];
    float sp = 0.f;
#pragma unroll
    for (int mi = 0; mi < 2; ++mi) {
      float e0 = __expf(acc[mi][nj][0] + bias);
      float e1 = __expf(acc[mi][nj][1] + bias);
      float e2 = __expf(acc[mi][nj][2] + bias);
      float e3 = __expf(acc[mi][nj][3] + bias);
      sp += e0 + e1 + e2 + e3;
      ushort4 u;
      u.x = f2bf(e0); u.y = f2bf(e1); u.z = f2bf(e2); u.w = f2bf(e3);
      *(ushort4*)&attbf[(size_t)(b * 512 + t * 64 + a) * HW + pw + mi * 16 + kg * 4] = u;
    }
    sp += __shfl_xor(sp, 16);
    sp += __shfl_xor(sp, 32);
    rowpart[nj] = sp;
  }
  if (lane < 16) {
#pragma unroll
    for (int nj = 0; nj < 4; ++nj) wsum[wave][nj * 16 + r] = rowpart[nj];
  }
  __syncthreads();
  if (tid < 64) {
    float tot = wsum[0][tid] + wsum[1][tid] + wsum[2][tid] + wsum[3][tid];
    rsum_part[(size_t)blockIdx.x * 4096 + b * 512 + t * 64 + tid] = tot;
  }
}

// ---------------------------------------------------------------------------
// k_rsum: rsum[row] = sum_{pblk<32} rsum_part[pblk][row].  16 blocks x 256.
// ---------------------------------------------------------------------------
__global__ __launch_bounds__(256) void k_rsum(
    const float* __restrict__ rsum_part, float* __restrict__ rsum) {
  const int row = blockIdx.x * 256 + threadIdx.x;
  float s = 0.f;
#pragma unroll
  for (int j = 0; j < 32; ++j) s += rsum_part[(size_t)j * 4096 + row];
  rsum[row] = s;
}

// ---------------------------------------------------------------------------
// k_ctx: split-K(8) partial GEMM + BALANCED fused attn output.
//   partial[kc][b][f][a] = sum_{p in kc-chunk} feat[b,f,p]*e[b,a,p]
//   Each block writes the attn f32 output for its (rows, kc-chunk) where
//   ch == ft  ->  every block writes exactly 64 rows x 256 cols (64 KB).
// A = featbf direct global (K-contig), B = attbf staged in LDS.
// Block: 128f x 64a, K = 512.  Grid (8 atile, 2 ftile, 64 = b*8+kc).
// ---------------------------------------------------------------------------
__global__ __launch_bounds__(256) void k_ctx(
    const unsigned short* __restrict__ featbf,
    const unsigned short* __restrict__ attbf,
    const float* __restrict__ rsum,
    float* __restrict__ partial,
    float* __restrict__ attn) {
  const int a0 = blockIdx.x * 64;
  const int ft = blockIdx.y;
  const int b  = blockIdx.z >> 3;
  const int kc = blockIdx.z & 7;
  __shared__ unsigned short Bsh[64 * LROW];    // 33.8 KB
  const int tid = threadIdx.x, lane = tid & 63, wave = tid >> 6;
  const int r = lane & 15, kg = lane >> 4;
  const int fbase = ft * 128 + wave * 32;
  const int brow = tid >> 2;            // 0..63  (a-row within tile)
  const int bseg = (tid & 3) * 64;      // col segment within 256-chunk
  const unsigned short* Arow = featbf + (size_t)(b * 256 + fbase + r) * HW + kc * 512 + kg * 8;
  const unsigned short* Bsrc = attbf + (size_t)(b * 512 + a0 + brow) * HW + kc * 512 + bseg;
  unsigned short* Bdst = &Bsh[brow * LROW + bseg];
  float* attn_row = attn + (size_t)(b * 512 + a0 + brow) * HW + kc * 512 + bseg;
  const float inv = 1.0f / rsum[b * 512 + a0 + brow];
  f32x4 acc[2][4] = {};
  for (int ch = 0; ch < 2; ++ch) {
    __syncthreads();
#pragma unroll
    for (int i = 0; i < 8; ++i) {
      short8 v = *(const short8*)(Bsrc + ch * 256 + i * 8);
      *(short8*)(Bdst + i * 8) = v;
      if (ch == ft) {   // balanced: ft==0 writes chunk 0, ft==1 writes chunk 1
        float4 o0, o1;
        o0.x = bf2f((unsigned short)v[0]) * inv;
        o0.y = bf2f((unsigned short)v[1]) * inv;
        o0.z = bf2f((unsigned short)v[2]) * inv;
        o0.w = bf2f((unsigned short)v[3]) * inv;
        o1.x = bf2f((unsigned short)v[4]) * inv;
        o1.y = bf2f((unsigned short)v[5]) * inv;
        o1.z = bf2f((unsigned short)v[6]) * inv;
        o1.w = bf2f((unsigned short)v[7]) * inv;
        *(float4*)(attn_row + ch * 256 + i * 8) = o0;
        *(float4*)(attn_row + ch * 256 + i * 8 + 4) = o1;
      }
    }
    __syncthreads();
#pragma unroll
    for (int ks = 0; ks < 8; ++ks) {
      short8 afr[2];
      afr[0] = *(const short8*)(Arow + ch * 256 + ks * 32);
      afr[1] = *(const short8*)(Arow + ch * 256 + ks * 32 + (size_t)16 * HW);
      short8 bfr[4];
#pragma unroll
      for (int nj = 0; nj < 4; ++nj)
        bfr[nj] = *(const short8*)&Bsh[(nj * 16 + r) * LROW + ks * 32 + kg * 8];
#pragma unroll
      for (int mi = 0; mi < 2; ++mi)
#pragma unroll
        for (int nj = 0; nj < 4; ++nj)
          acc[mi][nj] = __builtin_amdgcn_mfma_f32_16x16x32_bf16(afr[mi], bfr[nj], acc[mi][nj], 0, 0, 0);
    }
  }
  const size_t base = ((size_t)kc << 20) + (size_t)b * (256 * 512);
#pragma unroll
  for (int mi = 0; mi < 2; ++mi)
#pragma unroll
    for (int nj = 0; nj < 4; ++nj)
#pragma unroll
      for (int reg = 0; reg < 4; ++reg) {
        const int f = fbase + mi * 16 + kg * 4 + reg;
        const int a = a0 + nj * 16 + r;
        partial[base + (size_t)f * 512 + a] = acc[mi][nj][reg];
      }
}

// ---------------------------------------------------------------------------
// k_ctxred: ctx[idx] = (sum_{kc<8} partial[kc][idx]) / rsum[row_a]
// ---------------------------------------------------------------------------
__global__ __launch_bounds__(256) void k_ctxred(
    const float* __restrict__ partial, const float* __restrict__ rsum,
    float* __restrict__ ctx) {
  const int idx = blockIdx.x * 256 + threadIdx.x;
  const int a = idx & 511, b = idx >> 17;
  float s = 0.f;
#pragma unroll
  for (int kc = 0; kc < 8; ++kc) s += partial[((size_t)kc << 20) + idx];
  ctx[idx] = s / rsum[b * 512 + a];
}

// ---------------------------------------------------------------------------
extern "C" void kernel_launch(void* const* d_in, const int* in_sizes, int n_in,
                              void* d_out, int out_size, void* d_ws, size_t ws_size,
                              hipStream_t stream) {
  const float* x     = (const float*)d_in[0];
  const float* Wf    = (const float*)d_in[1];
  const float* bfeat = (const float*)d_in[2];
  const float* Wa    = (const float*)d_in[3];
  const float* ba    = (const float*)d_in[4];
  float* ctx  = (float*)d_out;
  float* attn = ctx + CTX_ELEMS;

  unsigned short* featbf = (unsigned short*)d_ws;                 // 16.8 MB
  unsigned short* attbf  = featbf + (size_t)NB * 256 * HW;        // 33.6 MB
  float* rsum_part = (float*)(attbf + (size_t)4096 * HW);         // 512 KB
  float* rsum = rsum_part + 32 * 4096;                            // 16 KB
  float* partial = rsum + 4096;                                   // 33.6 MB (8 x 4 MB)

  k_feat<<<dim3(32, 2, NB), 256, 0, stream>>>(x, Wf, bfeat, featbf);
  k_att<<<dim3(32, 64), 256, 0, stream>>>(x, Wa, ba, attbf, rsum_part);
  k_rsum<<<16, 256, 0, stream>>>(rsum_part, rsum);
  k_ctx<<<dim3(8, 2, 64), 256, 0, stream>>>(featbf, attbf, rsum, partial, attn);
  k_ctxred<<<4096, 256, 0, stream>>>(partial, rsum, ctx);
}

// Round 6
// 166.583 us; speedup vs baseline: 1.0698x; 1.0441x over previous
//
#include <hip/hip_runtime.h>
#include <hip/hip_bf16.h>

#define HW    4096
#define CIN   256
#define NB    8
#define T_FR  8
#define CTX_ELEMS (NB * 256 * 512)      // 1,048,576 = 2^20

typedef __attribute__((ext_vector_type(8))) short short8;
typedef __attribute__((ext_vector_type(4))) float f32x4;

__device__ __forceinline__ unsigned short f2bf(float f) {
  union { float f; unsigned int u; } v; v.f = f;
  unsigned int r = v.u + 0x7fffu + ((v.u >> 16) & 1u);   // RNE
  return (unsigned short)(r >> 16);
}
__device__ __forceinline__ float bf2f(unsigned short u) {
  union { unsigned int u; float f; } v; v.u = ((unsigned int)u) << 16;
  return v.f;
}

// ---------------------------------------------------------------------------
// k_feat: feat[b,f,p] = sum_c x[b*T, c, p] * Wf[f,c] + bias  -> bf16 ws
// A = x^T (per-lane direct global column-gather, f32->bf16 cvt),
// B = Wf tile (n = 128 f) staged bf16 in LDS (264-short padded rows).
// ---------------------------------------------------------------------------
#define LROW 264
__global__ __launch_bounds__(256) void k_feat(
    const float* __restrict__ x, const float* __restrict__ Wf,
    const float* __restrict__ bfeat, unsigned short* __restrict__ featbf) {
  const int p0  = blockIdx.x * 128;
  const int f0t = blockIdx.y * 128;
  const int b   = blockIdx.z;
  __shared__ unsigned short Wsh[128 * LROW];   // 67.6 KB
  const int tid = threadIdx.x, lane = tid & 63, wave = tid >> 6;
  {
    const int row = tid >> 1, seg = tid & 1;
    const float* src = Wf + (size_t)(f0t + row) * CIN + seg * 128;
    unsigned short* dst = &Wsh[row * LROW + seg * 128];
#pragma unroll
    for (int i = 0; i < 16; ++i) {
      float4 va = *(const float4*)(src + i * 8);
      float4 vb = *(const float4*)(src + i * 8 + 4);
      short8 w;
      w[0] = (short)f2bf(va.x); w[1] = (short)f2bf(va.y);
      w[2] = (short)f2bf(va.z); w[3] = (short)f2bf(va.w);
      w[4] = (short)f2bf(vb.x); w[5] = (short)f2bf(vb.y);
      w[6] = (short)f2bf(vb.z); w[7] = (short)f2bf(vb.w);
      *(short8*)(dst + i * 8) = w;
    }
  }
  __syncthreads();
  const int r = lane & 15, kg = lane >> 4;
  const int pw = p0 + wave * 32;
  const float* xs = x + (size_t)(b * T_FR) * CIN * HW;   // frame 0 of clip b
  f32x4 acc[2][8] = {};
  for (int ks = 0; ks < 8; ++ks) {
    short8 afr[2];
#pragma unroll
    for (int mi = 0; mi < 2; ++mi) {
      const float* col = xs + (size_t)(ks * 32 + kg * 8) * HW + pw + mi * 16 + r;
#pragma unroll
      for (int j = 0; j < 8; ++j) afr[mi][j] = (short)f2bf(col[(size_t)j * HW]);
    }
    short8 bfr[8];
#pragma unroll
    for (int nj = 0; nj < 8; ++nj)
      bfr[nj] = *(const short8*)&Wsh[(nj * 16 + r) * LROW + ks * 32 + kg * 8];
#pragma unroll
    for (int mi = 0; mi < 2; ++mi)
#pragma unroll
      for (int nj = 0; nj < 8; ++nj)
        acc[mi][nj] = __builtin_amdgcn_mfma_f32_16x16x32_bf16(afr[mi], bfr[nj], acc[mi][nj], 0, 0, 0);
  }
#pragma unroll
  for (int nj = 0; nj < 8; ++nj) {
    const int f = f0t + nj * 16 + r;
    const float bias = bfeat[f];
#pragma unroll
    for (int mi = 0; mi < 2; ++mi) {
      ushort4 u;
      u.x = f2bf(acc[mi][nj][0] + bias);
      u.y = f2bf(acc[mi][nj][1] + bias);
      u.z = f2bf(acc[mi][nj][2] + bias);
      u.w = f2bf(acc[mi][nj][3] + bias);
      *(ushort4*)&featbf[(size_t)(b * 256 + f) * HW + pw + mi * 16 + kg * 4] = u;
    }
  }
}

// ---------------------------------------------------------------------------
// k_att: logits = Wa @ x[s] + bias; e = exp(logit); store e (bf16) to ws;
// write per-pblock row-sum partials (deterministic, no atomics, no memset).
// ---------------------------------------------------------------------------
__global__ __launch_bounds__(256) void k_att(
    const float* __restrict__ x, const float* __restrict__ Wa,
    const float* __restrict__ batt, unsigned short* __restrict__ attbf,
    float* __restrict__ rsum_part) {
  const int p0 = blockIdx.x * 128;
  const int s  = blockIdx.y;
  __shared__ unsigned short Wsh[64 * LROW];    // 33.8 KB
  __shared__ float wsum[4][64];
  const int tid = threadIdx.x, lane = tid & 63, wave = tid >> 6;
  {
    const int row = tid >> 2, seg = tid & 3;
    const float* src = Wa + (size_t)row * CIN + seg * 64;
    unsigned short* dst = &Wsh[row * LROW + seg * 64];
#pragma unroll
    for (int i = 0; i < 8; ++i) {
      float4 va = *(const float4*)(src + i * 8);
      float4 vb = *(const float4*)(src + i * 8 + 4);
      short8 w;
      w[0] = (short)f2bf(va.x); w[1] = (short)f2bf(va.y);
      w[2] = (short)f2bf(va.z); w[3] = (short)f2bf(va.w);
      w[4] = (short)f2bf(vb.x); w[5] = (short)f2bf(vb.y);
      w[6] = (short)f2bf(vb.z); w[7] = (short)f2bf(vb.w);
      *(short8*)(dst + i * 8) = w;
    }
  }
  __syncthreads();
  const int r = lane & 15, kg = lane >> 4;
  const int pw = p0 + wave * 32;
  const float* xs = x + (size_t)s * CIN * HW;
  f32x4 acc[2][4] = {};
  for (int ks = 0; ks < 8; ++ks) {
    short8 afr[2];
#pragma unroll
    for (int mi = 0; mi < 2; ++mi) {
      const float* col = xs + (size_t)(ks * 32 + kg * 8) * HW + pw + mi * 16 + r;
#pragma unroll
      for (int j = 0; j < 8; ++j) afr[mi][j] = (short)f2bf(col[(size_t)j * HW]);
    }
    short8 bfr[4];
#pragma unroll
    for (int nj = 0; nj < 4; ++nj)
      bfr[nj] = *(const short8*)&Wsh[(nj * 16 + r) * LROW + ks * 32 + kg * 8];
#pragma unroll
    for (int mi = 0; mi < 2; ++mi)
#pragma unroll
      for (int nj = 0; nj < 4; ++nj)
        acc[mi][nj] = __builtin_amdgcn_mfma_f32_16x16x32_bf16(afr[mi], bfr[nj], acc[mi][nj], 0, 0, 0);
  }
  const int b = s >> 3, t = s & 7;
  float rowpart[4];
#pragma unroll
  for (int nj = 0; nj < 4; ++nj) {
    const int a = nj * 16 + r;
    const float bias = batt[a];
    float sp = 0.f;
#pragma unroll
    for (int mi = 0; mi < 2; ++mi) {
      float e0 = __expf(acc[mi][nj][0] + bias);
      float e1 = __expf(acc[mi][nj][1] + bias);
      float e2 = __expf(acc[mi][nj][2] + bias);
      float e3 = __expf(acc[mi][nj][3] + bias);
      sp += e0 + e1 + e2 + e3;
      ushort4 u;
      u.x = f2bf(e0); u.y = f2bf(e1); u.z = f2bf(e2); u.w = f2bf(e3);
      *(ushort4*)&attbf[(size_t)(b * 512 + t * 64 + a) * HW + pw + mi * 16 + kg * 4] = u;
    }
    sp += __shfl_xor(sp, 16);
    sp += __shfl_xor(sp, 32);
    rowpart[nj] = sp;
  }
  if (lane < 16) {
#pragma unroll
    for (int nj = 0; nj < 4; ++nj) wsum[wave][nj * 16 + r] = rowpart[nj];
  }
  __syncthreads();
  if (tid < 64) {
    float tot = wsum[0][tid] + wsum[1][tid] + wsum[2][tid] + wsum[3][tid];
    rsum_part[(size_t)blockIdx.x * 4096 + b * 512 + t * 64 + tid] = tot;
  }
}

// ---------------------------------------------------------------------------
// k_rsum: rsum[row] = sum_{pblk<32} rsum_part[pblk][row].  16 blocks x 256.
// ---------------------------------------------------------------------------
__global__ __launch_bounds__(256) void k_rsum(
    const float* __restrict__ rsum_part, float* __restrict__ rsum) {
  const int row = blockIdx.x * 256 + threadIdx.x;
  float s = 0.f;
#pragma unroll
  for (int j = 0; j < 32; ++j) s += rsum_part[(size_t)j * 4096 + row];
  rsum[row] = s;
}

// ---------------------------------------------------------------------------
// k_ctx: split-K(8) partial GEMM, 256f x 32a tile, B staged ONCE (2 barriers
// total).  partial[kc][b][f][a] = sum_{p in kc-chunk} feat[b,f,p]*e[b,a,p].
// A = featbf direct global (K-contig, LLC-resident), B = attbf in LDS
// ([32][520] shorts -> uniform-optimal bank spread for ds_read_b128).
// Grid (16 atile, 8 kc, 8 b) = 1024 blocks; 33.3 KB LDS -> 4 blocks/CU.
// ---------------------------------------------------------------------------
#define BROW 520
__global__ __launch_bounds__(256) void k_ctx(
    const unsigned short* __restrict__ featbf,
    const unsigned short* __restrict__ attbf,
    float* __restrict__ partial) {
  const int a0 = blockIdx.x * 32;
  const int kc = blockIdx.y;
  const int b  = blockIdx.z;
  __shared__ unsigned short Bsh[32 * BROW];    // 33.3 KB
  const int tid = threadIdx.x, lane = tid & 63, wave = tid >> 6;
  const int r = lane & 15, kg = lane >> 4;
  // stage B: 32 rows x 512 cols bf16, each thread 1 row-segment of 128B
  {
    const int row = tid >> 3, seg = tid & 7;
    const unsigned short* src = attbf + (size_t)(b * 512 + a0 + row) * HW + kc * 512 + seg * 64;
    unsigned short* dst = &Bsh[row * BROW + seg * 64];
#pragma unroll
    for (int i = 0; i < 8; ++i)
      *(short8*)(dst + i * 8) = *(const short8*)(src + i * 8);
  }
  __syncthreads();
  const unsigned short* Arow = featbf + (size_t)(b * 256 + wave * 64 + r) * HW + kc * 512 + kg * 8;
  f32x4 acc[4][2] = {};
#pragma unroll
  for (int ks = 0; ks < 16; ++ks) {
    short8 afr[4];
#pragma unroll
    for (int mi = 0; mi < 4; ++mi)
      afr[mi] = *(const short8*)(Arow + ks * 32 + (size_t)(mi * 16) * HW);
    short8 bfr[2];
#pragma unroll
    for (int nj = 0; nj < 2; ++nj)
      bfr[nj] = *(const short8*)&Bsh[(nj * 16 + r) * BROW + ks * 32 + kg * 8];
#pragma unroll
    for (int mi = 0; mi < 4; ++mi)
#pragma unroll
      for (int nj = 0; nj < 2; ++nj)
        acc[mi][nj] = __builtin_amdgcn_mfma_f32_16x16x32_bf16(afr[mi], bfr[nj], acc[mi][nj], 0, 0, 0);
  }
  const size_t base = ((size_t)kc << 20) + (size_t)b * (256 * 512);
#pragma unroll
  for (int mi = 0; mi < 4; ++mi)
#pragma unroll
    for (int nj = 0; nj < 2; ++nj)
#pragma unroll
      for (int reg = 0; reg < 4; ++reg) {
        const int f = wave * 64 + mi * 16 + kg * 4 + reg;
        const int a = a0 + nj * 16 + r;
        partial[base + (size_t)f * 512 + a] = acc[mi][nj][reg];
      }
}

// ---------------------------------------------------------------------------
// k_final: merged epilogue.
//   blocks [0,4096):    ctx[idx] = (sum_kc partial[kc][idx]) / rsum[row_a]
//   blocks [4096,8192): attn[row,:] = e_bf16[row,:] / rsum[row]
// ---------------------------------------------------------------------------
__global__ __launch_bounds__(256) void k_final(
    const float* __restrict__ partial, const float* __restrict__ rsum,
    const unsigned short* __restrict__ attbf,
    float* __restrict__ ctx, float* __restrict__ attn) {
  if (blockIdx.x < 4096) {
    const int idx = blockIdx.x * 256 + threadIdx.x;
    const int a = idx & 511, b = idx >> 17;
    float s = 0.f;
#pragma unroll
    for (int kc = 0; kc < 8; ++kc) s += partial[((size_t)kc << 20) + idx];
    ctx[idx] = s / rsum[b * 512 + a];
  } else {
    const int row = blockIdx.x - 4096;
    const float inv = 1.0f / rsum[row];
    const unsigned short* src = attbf + (size_t)row * HW;
    float* dst = attn + (size_t)row * HW;
    const int tid = threadIdx.x;
#pragma unroll
    for (int i = 0; i < 2; ++i) {
      short8 v = *(const short8*)(src + tid * 8 + i * 2048);
      float4 o0, o1;
      o0.x = bf2f((unsigned short)v[0]) * inv;
      o0.y = bf2f((unsigned short)v[1]) * inv;
      o0.z = bf2f((unsigned short)v[2]) * inv;
      o0.w = bf2f((unsigned short)v[3]) * inv;
      o1.x = bf2f((unsigned short)v[4]) * inv;
      o1.y = bf2f((unsigned short)v[5]) * inv;
      o1.z = bf2f((unsigned short)v[6]) * inv;
      o1.w = bf2f((unsigned short)v[7]) * inv;
      *(float4*)(dst + tid * 8 + i * 2048) = o0;
      *(float4*)(dst + tid * 8 + i * 2048 + 4) = o1;
    }
  }
}

// ---------------------------------------------------------------------------
extern "C" void kernel_launch(void* const* d_in, const int* in_sizes, int n_in,
                              void* d_out, int out_size, void* d_ws, size_t ws_size,
                              hipStream_t stream) {
  const float* x     = (const float*)d_in[0];
  const float* Wf    = (const float*)d_in[1];
  const float* bfeat = (const float*)d_in[2];
  const float* Wa    = (const float*)d_in[3];
  const float* ba    = (const float*)d_in[4];
  float* ctx  = (float*)d_out;
  float* attn = ctx + CTX_ELEMS;

  unsigned short* featbf = (unsigned short*)d_ws;                 // 16.8 MB
  unsigned short* attbf  = featbf + (size_t)NB * 256 * HW;        // 33.6 MB
  float* rsum_part = (float*)(attbf + (size_t)4096 * HW);         // 512 KB
  float* rsum = rsum_part + 32 * 4096;                            // 16 KB
  float* partial = rsum + 4096;                                   // 33.6 MB (8 x 4 MB)

  // k_att first so featbf (written by k_feat) is LLC-hot for k_ctx.
  k_att<<<dim3(32, 64), 256, 0, stream>>>(x, Wa, ba, attbf, rsum_part);
  k_feat<<<dim3(32, 2, NB), 256, 0, stream>>>(x, Wf, bfeat, featbf);
  k_rsum<<<16, 256, 0, stream>>>(rsum_part, rsum);
  k_ctx<<<dim3(16, 8, NB), 256, 0, stream>>>(featbf, attbf, partial);
  k_final<<<8192, 256, 0, stream>>>(partial, rsum, attbf, ctx, attn);
}

// Round 7
// 146.340 us; speedup vs baseline: 1.2178x; 1.1383x over previous
//
#include <hip/hip_runtime.h>
#include <hip/hip_bf16.h>

#define HW    4096
#define CIN   256
#define NB    8
#define T_FR  8
#define CTX_ELEMS (NB * 256 * 512)      // 1,048,576 = 2^20

typedef __attribute__((ext_vector_type(8))) short short8;
typedef __attribute__((ext_vector_type(4))) float f32x4;

__device__ __forceinline__ unsigned short f2bf(float f) {
  union { float f; unsigned int u; } v; v.f = f;
  unsigned int r = v.u + 0x7fffu + ((v.u >> 16) & 1u);   // RNE
  return (unsigned short)(r >> 16);
}
__device__ __forceinline__ float bf2f(unsigned short u) {
  union { unsigned int u; float f; } v; v.u = ((unsigned int)u) << 16;
  return v.f;
}

// ---------------------------------------------------------------------------
// k_main: merged att + feat (block-uniform branch, identical tile shapes).
//   blocks [0,2048):    att: (pb = bid&31, s = bid>>5)
//     logits = Wa @ x[s]; e = exp(logit+bias); attbf bf16; rsum partials.
//   blocks [2048,3072): feat: (pb, g = (bid-2048)>>5, ftile = g&3, b = g>>2)
//     feat = Wf[ftile*64:+64] @ x[b*T,:] + bias -> featbf bf16.
// Both: A = x^T per-lane direct global gather (f32->bf16), B = 64xCIN weight
// slice staged bf16 in LDS (264-short padded rows).  34.8 KB LDS, 4 blk/CU.
// ---------------------------------------------------------------------------
#define LROW 264
__global__ __launch_bounds__(256) void k_main(
    const float* __restrict__ x, const float* __restrict__ Wa,
    const float* __restrict__ Wf, const float* __restrict__ batt,
    const float* __restrict__ bfeat, unsigned short* __restrict__ attbf,
    unsigned short* __restrict__ featbf, float* __restrict__ rsum_part) {
  const int bid = blockIdx.x;
  __shared__ unsigned short Wsh[64 * LROW];    // 33.8 KB
  __shared__ float wsum[4][64];
  const int tid = threadIdx.x, lane = tid & 63, wave = tid >> 6;

  const bool is_att = bid < 2048;
  int pb, s, ftile, b;
  const float* Wsrc;
  if (is_att) {
    pb = bid & 31; s = bid >> 5; ftile = 0; b = 0;
    Wsrc = Wa;
  } else {
    const int fb = bid - 2048;
    pb = fb & 31;
    const int g = fb >> 5;
    ftile = g & 3; b = g >> 2; s = b * T_FR;   // frame 0 of clip b
    Wsrc = Wf + (size_t)(ftile * 64) * CIN;
  }

  // stage 64 rows x 256 cols of Wsrc -> bf16 LDS
  {
    const int row = tid >> 2, seg = tid & 3;
    const float* src = Wsrc + (size_t)row * CIN + seg * 64;
    unsigned short* dst = &Wsh[row * LROW + seg * 64];
#pragma unroll
    for (int i = 0; i < 8; ++i) {
      float4 va = *(const float4*)(src + i * 8);
      float4 vb = *(const float4*)(src + i * 8 + 4);
      short8 w;
      w[0] = (short)f2bf(va.x); w[1] = (short)f2bf(va.y);
      w[2] = (short)f2bf(va.z); w[3] = (short)f2bf(va.w);
      w[4] = (short)f2bf(vb.x); w[5] = (short)f2bf(vb.y);
      w[6] = (short)f2bf(vb.z); w[7] = (short)f2bf(vb.w);
      *(short8*)(dst + i * 8) = w;
    }
  }
  __syncthreads();

  const int r = lane & 15, kg = lane >> 4;
  const int pw = pb * 128 + wave * 32;
  const float* xs = x + (size_t)s * CIN * HW;
  f32x4 acc[2][4] = {};
  for (int ks = 0; ks < 8; ++ks) {
    short8 afr[2];
#pragma unroll
    for (int mi = 0; mi < 2; ++mi) {
      const float* col = xs + (size_t)(ks * 32 + kg * 8) * HW + pw + mi * 16 + r;
#pragma unroll
      for (int j = 0; j < 8; ++j) afr[mi][j] = (short)f2bf(col[(size_t)j * HW]);
    }
    short8 bfr[4];
#pragma unroll
    for (int nj = 0; nj < 4; ++nj)
      bfr[nj] = *(const short8*)&Wsh[(nj * 16 + r) * LROW + ks * 32 + kg * 8];
#pragma unroll
    for (int mi = 0; mi < 2; ++mi)
#pragma unroll
      for (int nj = 0; nj < 4; ++nj)
        acc[mi][nj] = __builtin_amdgcn_mfma_f32_16x16x32_bf16(afr[mi], bfr[nj], acc[mi][nj], 0, 0, 0);
  }

  if (is_att) {
    const int bb = s >> 3, t = s & 7;
    float rowpart[4];
#pragma unroll
    for (int nj = 0; nj < 4; ++nj) {
      const int a = nj * 16 + r;
      const float bias = batt[a];
      float sp = 0.f;
#pragma unroll
      for (int mi = 0; mi < 2; ++mi) {
        float e0 = __expf(acc[mi][nj][0] + bias);
        float e1 = __expf(acc[mi][nj][1] + bias);
        float e2 = __expf(acc[mi][nj][2] + bias);
        float e3 = __expf(acc[mi][nj][3] + bias);
        sp += e0 + e1 + e2 + e3;
        ushort4 u;
        u.x = f2bf(e0); u.y = f2bf(e1); u.z = f2bf(e2); u.w = f2bf(e3);
        *(ushort4*)&attbf[(size_t)(bb * 512 + t * 64 + a) * HW + pw + mi * 16 + kg * 4] = u;
      }
      sp += __shfl_xor(sp, 16);
      sp += __shfl_xor(sp, 32);
      rowpart[nj] = sp;
    }
    if (lane < 16) {
#pragma unroll
      for (int nj = 0; nj < 4; ++nj) wsum[wave][nj * 16 + r] = rowpart[nj];
    }
    __syncthreads();
    if (tid < 64) {
      float tot = wsum[0][tid] + wsum[1][tid] + wsum[2][tid] + wsum[3][tid];
      rsum_part[(size_t)pb * 4096 + bb * 512 + t * 64 + tid] = tot;
    }
  } else {
#pragma unroll
    for (int nj = 0; nj < 4; ++nj) {
      const int f = ftile * 64 + nj * 16 + r;
      const float bias = bfeat[f];
#pragma unroll
      for (int mi = 0; mi < 2; ++mi) {
        ushort4 u;
        u.x = f2bf(acc[mi][nj][0] + bias);
        u.y = f2bf(acc[mi][nj][1] + bias);
        u.z = f2bf(acc[mi][nj][2] + bias);
        u.w = f2bf(acc[mi][nj][3] + bias);
        *(ushort4*)&featbf[(size_t)(b * 256 + f) * HW + pw + mi * 16 + kg * 4] = u;
      }
    }
  }
}

// ---------------------------------------------------------------------------
// k_rsum: rsum[row] = sum_{pblk<32} rsum_part[pblk][row].  16 blocks x 256.
// ---------------------------------------------------------------------------
__global__ __launch_bounds__(256) void k_rsum(
    const float* __restrict__ rsum_part, float* __restrict__ rsum) {
  const int row = blockIdx.x * 256 + threadIdx.x;
  float s = 0.f;
#pragma unroll
  for (int j = 0; j < 32; ++j) s += rsum_part[(size_t)j * 4096 + row];
  rsum[row] = s;
}

// ---------------------------------------------------------------------------
// k_ctx: split-K(8) partial GEMM (round-3 proven version, verbatim).
//   partial[kc][b][f][a] = sum_{p in kc-chunk} feat[b,f,p]*e[b,a,p]
// A = featbf direct global (K-contig), B = attbf staged in LDS.
// Block: 128f x 64a, K = 512.  Grid (8 atile, 2 ftile, 64 = b*8+kc).
// ---------------------------------------------------------------------------
__global__ __launch_bounds__(256) void k_ctx(
    const unsigned short* __restrict__ featbf,
    const unsigned short* __restrict__ attbf,
    float* __restrict__ partial) {
  const int a0 = blockIdx.x * 64;
  const int ft = blockIdx.y;
  const int b  = blockIdx.z >> 3;
  const int kc = blockIdx.z & 7;
  __shared__ unsigned short Bsh[64 * LROW];    // 33.8 KB
  const int tid = threadIdx.x, lane = tid & 63, wave = tid >> 6;
  const int r = lane & 15, kg = lane >> 4;
  const int fbase = ft * 128 + wave * 32;
  const unsigned short* Arow = featbf + (size_t)(b * 256 + fbase + r) * HW + kc * 512 + kg * 8;
  const unsigned short* Bsrc = attbf + (size_t)(b * 512 + a0 + (tid >> 2)) * HW + kc * 512 + (tid & 3) * 64;
  unsigned short* Bdst = &Bsh[(tid >> 2) * LROW + (tid & 3) * 64];
  f32x4 acc[2][4] = {};
  for (int ch = 0; ch < 2; ++ch) {
    __syncthreads();
#pragma unroll
    for (int i = 0; i < 8; ++i)
      *(short8*)(Bdst + i * 8) = *(const short8*)(Bsrc + ch * 256 + i * 8);
    __syncthreads();
#pragma unroll
    for (int ks = 0; ks < 8; ++ks) {
      short8 afr[2];
      afr[0] = *(const short8*)(Arow + ch * 256 + ks * 32);
      afr[1] = *(const short8*)(Arow + ch * 256 + ks * 32 + (size_t)16 * HW);
      short8 bfr[4];
#pragma unroll
      for (int nj = 0; nj < 4; ++nj)
        bfr[nj] = *(const short8*)&Bsh[(nj * 16 + r) * LROW + ks * 32 + kg * 8];
#pragma unroll
      for (int mi = 0; mi < 2; ++mi)
#pragma unroll
        for (int nj = 0; nj < 4; ++nj)
          acc[mi][nj] = __builtin_amdgcn_mfma_f32_16x16x32_bf16(afr[mi], bfr[nj], acc[mi][nj], 0, 0, 0);
    }
  }
  const size_t base = ((size_t)kc << 20) + (size_t)b * (256 * 512);
#pragma unroll
  for (int mi = 0; mi < 2; ++mi)
#pragma unroll
    for (int nj = 0; nj < 4; ++nj)
#pragma unroll
      for (int reg = 0; reg < 4; ++reg) {
        const int f = fbase + mi * 16 + kg * 4 + reg;
        const int a = a0 + nj * 16 + r;
        partial[base + (size_t)f * 512 + a] = acc[mi][nj][reg];
      }
}

// ---------------------------------------------------------------------------
// k_final: merged epilogue.
//   blocks [0,1024):    ctxred, float4-vectorized:
//       ctx[i4..i4+3] = (sum_kc partial[kc][i4..]) / rsum[b*512 + (i4&511)..]
//   blocks [1024,5120): attn[row,:] = e_bf16[row,:] / rsum[row]
// ---------------------------------------------------------------------------
__global__ __launch_bounds__(256) void k_final(
    const float* __restrict__ partial, const float* __restrict__ rsum,
    const unsigned short* __restrict__ attbf,
    float* __restrict__ ctx, float* __restrict__ attn) {
  if (blockIdx.x < 1024) {
    const int i4 = (blockIdx.x * 256 + threadIdx.x) * 4;
    const int a = i4 & 511, b = i4 >> 17;
    float4 s = *(const float4*)&partial[i4];
#pragma unroll
    for (int kc = 1; kc < 8; ++kc) {
      float4 p = *(const float4*)&partial[((size_t)kc << 20) + i4];
      s.x += p.x; s.y += p.y; s.z += p.z; s.w += p.w;
    }
    const float4 rs = *(const float4*)&rsum[b * 512 + a];
    s.x /= rs.x; s.y /= rs.y; s.z /= rs.z; s.w /= rs.w;
    *(float4*)&ctx[i4] = s;
  } else {
    const int row = blockIdx.x - 1024;
    const float inv = 1.0f / rsum[row];
    const unsigned short* src = attbf + (size_t)row * HW;
    float* dst = attn + (size_t)row * HW;
    const int tid = threadIdx.x;
#pragma unroll
    for (int i = 0; i < 2; ++i) {
      short8 v = *(const short8*)(src + tid * 8 + i * 2048);
      float4 o0, o1;
      o0.x = bf2f((unsigned short)v[0]) * inv;
      o0.y = bf2f((unsigned short)v[1]) * inv;
      o0.z = bf2f((unsigned short)v[2]) * inv;
      o0.w = bf2f((unsigned short)v[3]) * inv;
      o1.x = bf2f((unsigned short)v[4]) * inv;
      o1.y = bf2f((unsigned short)v[5]) * inv;
      o1.z = bf2f((unsigned short)v[6]) * inv;
      o1.w = bf2f((unsigned short)v[7]) * inv;
      *(float4*)(dst + tid * 8 + i * 2048) = o0;
      *(float4*)(dst + tid * 8 + i * 2048 + 4) = o1;
    }
  }
}

// ---------------------------------------------------------------------------
extern "C" void kernel_launch(void* const* d_in, const int* in_sizes, int n_in,
                              void* d_out, int out_size, void* d_ws, size_t ws_size,
                              hipStream_t stream) {
  const float* x     = (const float*)d_in[0];
  const float* Wf    = (const float*)d_in[1];
  const float* bfeat = (const float*)d_in[2];
  const float* Wa    = (const float*)d_in[3];
  const float* ba    = (const float*)d_in[4];
  float* ctx  = (float*)d_out;
  float* attn = ctx + CTX_ELEMS;

  unsigned short* featbf = (unsigned short*)d_ws;                 // 16.8 MB
  unsigned short* attbf  = featbf + (size_t)NB * 256 * HW;        // 33.6 MB
  float* rsum_part = (float*)(attbf + (size_t)4096 * HW);         // 512 KB
  float* rsum = rsum_part + 32 * 4096;                            // 16 KB
  float* partial = rsum + 4096;                                   // 33.6 MB (8 x 4 MB)

  k_main<<<3072, 256, 0, stream>>>(x, Wa, Wf, ba, bfeat, attbf, featbf, rsum_part);
  k_rsum<<<16, 256, 0, stream>>>(rsum_part, rsum);
  k_ctx<<<dim3(8, 2, 64), 256, 0, stream>>>(featbf, attbf, partial);
  k_final<<<5120, 256, 0, stream>>>(partial, rsum, attbf, ctx, attn);
}

// Round 8
// 143.808 us; speedup vs baseline: 1.2392x; 1.0176x over previous
//
#include <hip/hip_runtime.h>
#include <hip/hip_bf16.h>

#define HW    4096
#define CIN   256
#define NB    8
#define T_FR  8
#define CTX_ELEMS (NB * 256 * 512)      // 1,048,576 = 2^20

typedef __attribute__((ext_vector_type(8))) short short8;
typedef __attribute__((ext_vector_type(4))) float f32x4;

// RNE f32->bf16 via the HIP cast: compiler emits v_cvt_pk_bf16_f32 for pairs
// (manual bit-twiddle defeats that pattern-match; see T12/m240).
__device__ __forceinline__ unsigned short f2bf(float f) {
  __hip_bfloat16 h = __float2bfloat16(f);
  union { __hip_bfloat16 h; unsigned short u; } v; v.h = h;
  return v.u;
}
__device__ __forceinline__ float bf2f(unsigned short u) {
  union { unsigned int u; float f; } v; v.u = ((unsigned int)u) << 16;
  return v.f;
}

// ---------------------------------------------------------------------------
// k_main: merged att + feat (block-uniform branch, identical tile shapes).
//   blocks [0,2048):    att: (pb = bid&31, s = bid>>5)
//     logits = Wa @ x[s]; e = exp(logit+bias); attbf bf16; rsum partials.
//   blocks [2048,3072): feat: (pb, g = (bid-2048)>>5, ftile = g&3, b = g>>2)
//     feat = Wf[ftile*64:+64] @ x[b*T,:] + bias -> featbf bf16.
// Both: A = x^T per-lane direct global gather (f32->bf16), B = 64xCIN weight
// slice staged bf16 in LDS (264-short padded rows).  34.8 KB LDS, 4 blk/CU.
// ---------------------------------------------------------------------------
#define LROW 264
__global__ __launch_bounds__(256) void k_main(
    const float* __restrict__ x, const float* __restrict__ Wa,
    const float* __restrict__ Wf, const float* __restrict__ batt,
    const float* __restrict__ bfeat, unsigned short* __restrict__ attbf,
    unsigned short* __restrict__ featbf, float* __restrict__ rsum_part) {
  const int bid = blockIdx.x;
  __shared__ unsigned short Wsh[64 * LROW];    // 33.8 KB
  __shared__ float wsum[4][64];
  const int tid = threadIdx.x, lane = tid & 63, wave = tid >> 6;

  const bool is_att = bid < 2048;
  int pb, s, ftile, b;
  const float* Wsrc;
  if (is_att) {
    pb = bid & 31; s = bid >> 5; ftile = 0; b = 0;
    Wsrc = Wa;
  } else {
    const int fb = bid - 2048;
    pb = fb & 31;
    const int g = fb >> 5;
    ftile = g & 3; b = g >> 2; s = b * T_FR;   // frame 0 of clip b
    Wsrc = Wf + (size_t)(ftile * 64) * CIN;
  }

  // stage 64 rows x 256 cols of Wsrc -> bf16 LDS
  {
    const int row = tid >> 2, seg = tid & 3;
    const float* src = Wsrc + (size_t)row * CIN + seg * 64;
    unsigned short* dst = &Wsh[row * LROW + seg * 64];
#pragma unroll
    for (int i = 0; i < 8; ++i) {
      float4 va = *(const float4*)(src + i * 8);
      float4 vb = *(const float4*)(src + i * 8 + 4);
      short8 w;
      w[0] = (short)f2bf(va.x); w[1] = (short)f2bf(va.y);
      w[2] = (short)f2bf(va.z); w[3] = (short)f2bf(va.w);
      w[4] = (short)f2bf(vb.x); w[5] = (short)f2bf(vb.y);
      w[6] = (short)f2bf(vb.z); w[7] = (short)f2bf(vb.w);
      *(short8*)(dst + i * 8) = w;
    }
  }
  __syncthreads();

  const int r = lane & 15, kg = lane >> 4;
  const int pw = pb * 128 + wave * 32;
  const float* xs = x + (size_t)s * CIN * HW;
  f32x4 acc[2][4] = {};
  for (int ks = 0; ks < 8; ++ks) {
    short8 afr[2];
#pragma unroll
    for (int mi = 0; mi < 2; ++mi) {
      const float* col = xs + (size_t)(ks * 32 + kg * 8) * HW + pw + mi * 16 + r;
#pragma unroll
      for (int j = 0; j < 8; ++j) afr[mi][j] = (short)f2bf(col[(size_t)j * HW]);
    }
    short8 bfr[4];
#pragma unroll
    for (int nj = 0; nj < 4; ++nj)
      bfr[nj] = *(const short8*)&Wsh[(nj * 16 + r) * LROW + ks * 32 + kg * 8];
#pragma unroll
    for (int mi = 0; mi < 2; ++mi)
#pragma unroll
      for (int nj = 0; nj < 4; ++nj)
        acc[mi][nj] = __builtin_amdgcn_mfma_f32_16x16x32_bf16(afr[mi], bfr[nj], acc[mi][nj], 0, 0, 0);
  }

  if (is_att) {
    const int bb = s >> 3, t = s & 7;
    float rowpart[4];
#pragma unroll
    for (int nj = 0; nj < 4; ++nj) {
      const int a = nj * 16 + r;
      const float bias = batt[a];
      float sp = 0.f;
#pragma unroll
      for (int mi = 0; mi < 2; ++mi) {
        float e0 = __expf(acc[mi][nj][0] + bias);
        float e1 = __expf(acc[mi][nj][1] + bias);
        float e2 = __expf(acc[mi][nj][2] + bias);
        float e3 = __expf(acc[mi][nj][3] + bias);
        sp += e0 + e1 + e2 + e3;
        ushort4 u;
        u.x = f2bf(e0); u.y = f2bf(e1); u.z = f2bf(e2); u.w = f2bf(e3);
        *(ushort4*)&attbf[(size_t)(bb * 512 + t * 64 + a) * HW + pw + mi * 16 + kg * 4] = u;
      }
      sp += __shfl_xor(sp, 16);
      sp += __shfl_xor(sp, 32);
      rowpart[nj] = sp;
    }
    if (lane < 16) {
#pragma unroll
      for (int nj = 0; nj < 4; ++nj) wsum[wave][nj * 16 + r] = rowpart[nj];
    }
    __syncthreads();
    if (tid < 64) {
      float tot = wsum[0][tid] + wsum[1][tid] + wsum[2][tid] + wsum[3][tid];
      rsum_part[(size_t)pb * 4096 + bb * 512 + t * 64 + tid] = tot;
    }
  } else {
#pragma unroll
    for (int nj = 0; nj < 4; ++nj) {
      const int f = ftile * 64 + nj * 16 + r;
      const float bias = bfeat[f];
#pragma unroll
      for (int mi = 0; mi < 2; ++mi) {
        ushort4 u;
        u.x = f2bf(acc[mi][nj][0] + bias);
        u.y = f2bf(acc[mi][nj][1] + bias);
        u.z = f2bf(acc[mi][nj][2] + bias);
        u.w = f2bf(acc[mi][nj][3] + bias);
        *(ushort4*)&featbf[(size_t)(b * 256 + f) * HW + pw + mi * 16 + kg * 4] = u;
      }
    }
  }
}

// ---------------------------------------------------------------------------
// k_ctx: split-K(8) partial GEMM (proven inner loop) + fused rsum reduction.
//   Prologue: the 16 blocks with (x==0, y==0, z<16) also compute
//   rsum[row] = sum_{pblk<32} rsum_part[pblk][row]  (row = z*256+tid).
//   rsum is consumed only by k_final (next kernel) -> safe.
//   partial[kc][b][f][a] = sum_{p in kc-chunk} feat[b,f,p]*e[b,a,p]
// A = featbf direct global (K-contig), B = attbf staged in LDS.
// Block: 128f x 64a, K = 512.  Grid (8 atile, 2 ftile, 64 = b*8+kc).
// ---------------------------------------------------------------------------
__global__ __launch_bounds__(256) void k_ctx(
    const unsigned short* __restrict__ featbf,
    const unsigned short* __restrict__ attbf,
    const float* __restrict__ rsum_part,
    float* __restrict__ rsum,
    float* __restrict__ partial) {
  const int a0 = blockIdx.x * 64;
  const int ft = blockIdx.y;
  const int b  = blockIdx.z >> 3;
  const int kc = blockIdx.z & 7;
  const int tid = threadIdx.x, lane = tid & 63, wave = tid >> 6;

  // fused rsum: 16 blocks x 256 threads cover all 4096 rows
  if (blockIdx.x == 0 && blockIdx.y == 0 && blockIdx.z < 16) {
    const int row = blockIdx.z * 256 + tid;
    float s = 0.f;
#pragma unroll
    for (int j = 0; j < 32; ++j) s += rsum_part[(size_t)j * 4096 + row];
    rsum[row] = s;
  }

  __shared__ unsigned short Bsh[64 * LROW];    // 33.8 KB
  const int r = lane & 15, kg = lane >> 4;
  const int fbase = ft * 128 + wave * 32;
  const unsigned short* Arow = featbf + (size_t)(b * 256 + fbase + r) * HW + kc * 512 + kg * 8;
  const unsigned short* Bsrc = attbf + (size_t)(b * 512 + a0 + (tid >> 2)) * HW + kc * 512 + (tid & 3) * 64;
  unsigned short* Bdst = &Bsh[(tid >> 2) * LROW + (tid & 3) * 64];
  f32x4 acc[2][4] = {};
  for (int ch = 0; ch < 2; ++ch) {
    __syncthreads();
#pragma unroll
    for (int i = 0; i < 8; ++i)
      *(short8*)(Bdst + i * 8) = *(const short8*)(Bsrc + ch * 256 + i * 8);
    __syncthreads();
#pragma unroll
    for (int ks = 0; ks < 8; ++ks) {
      short8 afr[2];
      afr[0] = *(const short8*)(Arow + ch * 256 + ks * 32);
      afr[1] = *(const short8*)(Arow + ch * 256 + ks * 32 + (size_t)16 * HW);
      short8 bfr[4];
#pragma unroll
      for (int nj = 0; nj < 4; ++nj)
        bfr[nj] = *(const short8*)&Bsh[(nj * 16 + r) * LROW + ks * 32 + kg * 8];
#pragma unroll
      for (int mi = 0; mi < 2; ++mi)
#pragma unroll
        for (int nj = 0; nj < 4; ++nj)
          acc[mi][nj] = __builtin_amdgcn_mfma_f32_16x16x32_bf16(afr[mi], bfr[nj], acc[mi][nj], 0, 0, 0);
    }
  }
  const size_t base = ((size_t)kc << 20) + (size_t)b * (256 * 512);
#pragma unroll
  for (int mi = 0; mi < 2; ++mi)
#pragma unroll
    for (int nj = 0; nj < 4; ++nj)
#pragma unroll
      for (int reg = 0; reg < 4; ++reg) {
        const int f = fbase + mi * 16 + kg * 4 + reg;
        const int a = a0 + nj * 16 + r;
        partial[base + (size_t)f * 512 + a] = acc[mi][nj][reg];
      }
}

// ---------------------------------------------------------------------------
// k_final: merged epilogue.
//   blocks [0,1024):    ctxred, float4-vectorized:
//       ctx[i4..i4+3] = (sum_kc partial[kc][i4..]) / rsum[b*512 + (i4&511)..]
//   blocks [1024,5120): attn[row,:] = e_bf16[row,:] / rsum[row]
// ---------------------------------------------------------------------------
__global__ __launch_bounds__(256) void k_final(
    const float* __restrict__ partial, const float* __restrict__ rsum,
    const unsigned short* __restrict__ attbf,
    float* __restrict__ ctx, float* __restrict__ attn) {
  if (blockIdx.x < 1024) {
    const int i4 = (blockIdx.x * 256 + threadIdx.x) * 4;
    const int a = i4 & 511, b = i4 >> 17;
    float4 s = *(const float4*)&partial[i4];
#pragma unroll
    for (int kc = 1; kc < 8; ++kc) {
      float4 p = *(const float4*)&partial[((size_t)kc << 20) + i4];
      s.x += p.x; s.y += p.y; s.z += p.z; s.w += p.w;
    }
    const float4 rs = *(const float4*)&rsum[b * 512 + a];
    s.x /= rs.x; s.y /= rs.y; s.z /= rs.z; s.w /= rs.w;
    *(float4*)&ctx[i4] = s;
  } else {
    const int row = blockIdx.x - 1024;
    const float inv = 1.0f / rsum[row];
    const unsigned short* src = attbf + (size_t)row * HW;
    float* dst = attn + (size_t)row * HW;
    const int tid = threadIdx.x;
#pragma unroll
    for (int i = 0; i < 2; ++i) {
      short8 v = *(const short8*)(src + tid * 8 + i * 2048);
      float4 o0, o1;
      o0.x = bf2f((unsigned short)v[0]) * inv;
      o0.y = bf2f((unsigned short)v[1]) * inv;
      o0.z = bf2f((unsigned short)v[2]) * inv;
      o0.w = bf2f((unsigned short)v[3]) * inv;
      o1.x = bf2f((unsigned short)v[4]) * inv;
      o1.y = bf2f((unsigned short)v[5]) * inv;
      o1.z = bf2f((unsigned short)v[6]) * inv;
      o1.w = bf2f((unsigned short)v[7]) * inv;
      *(float4*)(dst + tid * 8 + i * 2048) = o0;
      *(float4*)(dst + tid * 8 + i * 2048 + 4) = o1;
    }
  }
}

// ---------------------------------------------------------------------------
extern "C" void kernel_launch(void* const* d_in, const int* in_sizes, int n_in,
                              void* d_out, int out_size, void* d_ws, size_t ws_size,
                              hipStream_t stream) {
  const float* x     = (const float*)d_in[0];
  const float* Wf    = (const float*)d_in[1];
  const float* bfeat = (const float*)d_in[2];
  const float* Wa    = (const float*)d_in[3];
  const float* ba    = (const float*)d_in[4];
  float* ctx  = (float*)d_out;
  float* attn = ctx + CTX_ELEMS;

  unsigned short* featbf = (unsigned short*)d_ws;                 // 16.8 MB
  unsigned short* attbf  = featbf + (size_t)NB * 256 * HW;        // 33.6 MB
  float* rsum_part = (float*)(attbf + (size_t)4096 * HW);         // 512 KB
  float* rsum = rsum_part + 32 * 4096;                            // 16 KB
  float* partial = rsum + 4096;                                   // 33.6 MB (8 x 4 MB)

  k_main<<<3072, 256, 0, stream>>>(x, Wa, Wf, ba, bfeat, attbf, featbf, rsum_part);
  k_ctx<<<dim3(8, 2, 64), 256, 0, stream>>>(featbf, attbf, rsum_part, rsum, partial);
  k_final<<<5120, 256, 0, stream>>>(partial, rsum, attbf, ctx, attn);
}

// Round 9
// 142.014 us; speedup vs baseline: 1.2549x; 1.0126x over previous
//
#include <hip/hip_runtime.h>
#include <hip/hip_bf16.h>

#define HW    4096
#define CIN   256
#define NB    8
#define T_FR  8
#define CTX_ELEMS (NB * 256 * 512)      // 1,048,576 = 2^20

typedef __attribute__((ext_vector_type(8))) short short8;
typedef __attribute__((ext_vector_type(4))) float f32x4;

__device__ __forceinline__ unsigned short f2bf(float f) {
  __hip_bfloat16 h = __float2bfloat16(f);
  union { __hip_bfloat16 h; unsigned short u; } v; v.h = h;
  return v.u;
}
__device__ __forceinline__ float bf2f(unsigned short u) {
  union { unsigned int u; float f; } v; v.u = ((unsigned int)u) << 16;
  return v.f;
}

// ---------------------------------------------------------------------------
// k_main: merged att + feat, 256-p tile (64 p per wave, acc[4][4]).
//   blocks [0,1024):    att: (pb = bid&15, s = bid>>4)
//   blocks [1024,1536): feat: (fb=bid-1024: pb = fb&15, g=fb>>4, ftile=g&3, b=g>>2)
// A = x^T per-lane direct global gather (f32->bf16) — 32 indep loads/K-step,
// B = 64xCIN weight slice staged bf16 in LDS.  33.8 KB LDS.
// ---------------------------------------------------------------------------
#define LROW 264
__global__ __launch_bounds__(256) void k_main(
    const float* __restrict__ x, const float* __restrict__ Wa,
    const float* __restrict__ Wf, const float* __restrict__ batt,
    const float* __restrict__ bfeat, unsigned short* __restrict__ attbf,
    unsigned short* __restrict__ featbf, float* __restrict__ rsum_part) {
  const int bid = blockIdx.x;
  __shared__ unsigned short Wsh[64 * LROW];    // 33.8 KB
  __shared__ float wsum[4][64];
  const int tid = threadIdx.x, lane = tid & 63, wave = tid >> 6;

  const bool is_att = bid < 1024;
  int pb, s, ftile, b;
  const float* Wsrc;
  if (is_att) {
    pb = bid & 15; s = bid >> 4; ftile = 0; b = 0;
    Wsrc = Wa;
  } else {
    const int fb = bid - 1024;
    pb = fb & 15;
    const int g = fb >> 4;
    ftile = g & 3; b = g >> 2; s = b * T_FR;   // frame 0 of clip b
    Wsrc = Wf + (size_t)(ftile * 64) * CIN;
  }

  // stage 64 rows x 256 cols of Wsrc -> bf16 LDS
  {
    const int row = tid >> 2, seg = tid & 3;
    const float* src = Wsrc + (size_t)row * CIN + seg * 64;
    unsigned short* dst = &Wsh[row * LROW + seg * 64];
#pragma unroll
    for (int i = 0; i < 8; ++i) {
      float4 va = *(const float4*)(src + i * 8);
      float4 vb = *(const float4*)(src + i * 8 + 4);
      short8 w;
      w[0] = (short)f2bf(va.x); w[1] = (short)f2bf(va.y);
      w[2] = (short)f2bf(va.z); w[3] = (short)f2bf(va.w);
      w[4] = (short)f2bf(vb.x); w[5] = (short)f2bf(vb.y);
      w[6] = (short)f2bf(vb.z); w[7] = (short)f2bf(vb.w);
      *(short8*)(dst + i * 8) = w;
    }
  }
  __syncthreads();

  const int r = lane & 15, kg = lane >> 4;
  const int pw = pb * 256 + wave * 64;
  const float* xs = x + (size_t)s * CIN * HW;
  f32x4 acc[4][4] = {};
  for (int ks = 0; ks < 8; ++ks) {
    short8 afr[4];
#pragma unroll
    for (int mi = 0; mi < 4; ++mi) {
      const float* col = xs + (size_t)(ks * 32 + kg * 8) * HW + pw + mi * 16 + r;
#pragma unroll
      for (int j = 0; j < 8; ++j) afr[mi][j] = (short)f2bf(col[(size_t)j * HW]);
    }
    short8 bfr[4];
#pragma unroll
    for (int nj = 0; nj < 4; ++nj)
      bfr[nj] = *(const short8*)&Wsh[(nj * 16 + r) * LROW + ks * 32 + kg * 8];
#pragma unroll
    for (int mi = 0; mi < 4; ++mi)
#pragma unroll
      for (int nj = 0; nj < 4; ++nj)
        acc[mi][nj] = __builtin_amdgcn_mfma_f32_16x16x32_bf16(afr[mi], bfr[nj], acc[mi][nj], 0, 0, 0);
  }

  if (is_att) {
    const int bb = s >> 3, t = s & 7;
    float rowpart[4];
#pragma unroll
    for (int nj = 0; nj < 4; ++nj) {
      const int a = nj * 16 + r;
      const float bias = batt[a];
      float sp = 0.f;
#pragma unroll
      for (int mi = 0; mi < 4; ++mi) {
        float e0 = __expf(acc[mi][nj][0] + bias);
        float e1 = __expf(acc[mi][nj][1] + bias);
        float e2 = __expf(acc[mi][nj][2] + bias);
        float e3 = __expf(acc[mi][nj][3] + bias);
        sp += e0 + e1 + e2 + e3;
        ushort4 u;
        u.x = f2bf(e0); u.y = f2bf(e1); u.z = f2bf(e2); u.w = f2bf(e3);
        *(ushort4*)&attbf[(size_t)(bb * 512 + t * 64 + a) * HW + pw + mi * 16 + kg * 4] = u;
      }
      sp += __shfl_xor(sp, 16);
      sp += __shfl_xor(sp, 32);
      rowpart[nj] = sp;
    }
    if (lane < 16) {
#pragma unroll
      for (int nj = 0; nj < 4; ++nj) wsum[wave][nj * 16 + r] = rowpart[nj];
    }
    __syncthreads();
    if (tid < 64) {
      float tot = wsum[0][tid] + wsum[1][tid] + wsum[2][tid] + wsum[3][tid];
      rsum_part[(size_t)pb * 4096 + bb * 512 + t * 64 + tid] = tot;
    }
  } else {
#pragma unroll
    for (int nj = 0; nj < 4; ++nj) {
      const int f = ftile * 64 + nj * 16 + r;
      const float bias = bfeat[f];
#pragma unroll
      for (int mi = 0; mi < 4; ++mi) {
        ushort4 u;
        u.x = f2bf(acc[mi][nj][0] + bias);
        u.y = f2bf(acc[mi][nj][1] + bias);
        u.z = f2bf(acc[mi][nj][2] + bias);
        u.w = f2bf(acc[mi][nj][3] + bias);
        *(ushort4*)&featbf[(size_t)(b * 256 + f) * HW + pw + mi * 16 + kg * 4] = u;
      }
    }
  }
}

// ---------------------------------------------------------------------------
// k_ctx: split-K(8) partial GEMM (proven inner loop) + fused rsum reduction.
//   Prologue: 16 blocks also reduce rsum_part (now 16 pblocks) -> rsum.
//   partial[kc][b][f][a] = sum_{p in kc-chunk} feat[b,f,p]*e[b,a,p]
// Block: 128f x 64a, K = 512.  Grid (8 atile, 2 ftile, 64 = b*8+kc).
// ---------------------------------------------------------------------------
__global__ __launch_bounds__(256) void k_ctx(
    const unsigned short* __restrict__ featbf,
    const unsigned short* __restrict__ attbf,
    const float* __restrict__ rsum_part,
    float* __restrict__ rsum,
    float* __restrict__ partial) {
  const int a0 = blockIdx.x * 64;
  const int ft = blockIdx.y;
  const int b  = blockIdx.z >> 3;
  const int kc = blockIdx.z & 7;
  const int tid = threadIdx.x, lane = tid & 63, wave = tid >> 6;

  // fused rsum: 16 blocks x 256 threads cover all 4096 rows
  if (blockIdx.x == 0 && blockIdx.y == 0 && blockIdx.z < 16) {
    const int row = blockIdx.z * 256 + tid;
    float s = 0.f;
#pragma unroll
    for (int j = 0; j < 16; ++j) s += rsum_part[(size_t)j * 4096 + row];
    rsum[row] = s;
  }

  __shared__ unsigned short Bsh[64 * LROW];    // 33.8 KB
  const int r = lane & 15, kg = lane >> 4;
  const int fbase = ft * 128 + wave * 32;
  const unsigned short* Arow = featbf + (size_t)(b * 256 + fbase + r) * HW + kc * 512 + kg * 8;
  const unsigned short* Bsrc = attbf + (size_t)(b * 512 + a0 + (tid >> 2)) * HW + kc * 512 + (tid & 3) * 64;
  unsigned short* Bdst = &Bsh[(tid >> 2) * LROW + (tid & 3) * 64];
  f32x4 acc[2][4] = {};
  for (int ch = 0; ch < 2; ++ch) {
    __syncthreads();
#pragma unroll
    for (int i = 0; i < 8; ++i)
      *(short8*)(Bdst + i * 8) = *(const short8*)(Bsrc + ch * 256 + i * 8);
    __syncthreads();
#pragma unroll
    for (int ks = 0; ks < 8; ++ks) {
      short8 afr[2];
      afr[0] = *(const short8*)(Arow + ch * 256 + ks * 32);
      afr[1] = *(const short8*)(Arow + ch * 256 + ks * 32 + (size_t)16 * HW);
      short8 bfr[4];
#pragma unroll
      for (int nj = 0; nj < 4; ++nj)
        bfr[nj] = *(const short8*)&Bsh[(nj * 16 + r) * LROW + ks * 32 + kg * 8];
#pragma unroll
      for (int mi = 0; mi < 2; ++mi)
#pragma unroll
        for (int nj = 0; nj < 4; ++nj)
          acc[mi][nj] = __builtin_amdgcn_mfma_f32_16x16x32_bf16(afr[mi], bfr[nj], acc[mi][nj], 0, 0, 0);
    }
  }
  const size_t base = ((size_t)kc << 20) + (size_t)b * (256 * 512);
#pragma unroll
  for (int mi = 0; mi < 2; ++mi)
#pragma unroll
    for (int nj = 0; nj < 4; ++nj)
#pragma unroll
      for (int reg = 0; reg < 4; ++reg) {
        const int f = fbase + mi * 16 + kg * 4 + reg;
        const int a = a0 + nj * 16 + r;
        partial[base + (size_t)f * 512 + a] = acc[mi][nj][reg];
      }
}

// ---------------------------------------------------------------------------
// k_final: merged epilogue.
//   blocks [0,1024):    ctxred, float4-vectorized.
//   blocks [1024,5120): attn[row,:] = e_bf16[row,:] / rsum[row]
// ---------------------------------------------------------------------------
__global__ __launch_bounds__(256) void k_final(
    const float* __restrict__ partial, const float* __restrict__ rsum,
    const unsigned short* __restrict__ attbf,
    float* __restrict__ ctx, float* __restrict__ attn) {
  if (blockIdx.x < 1024) {
    const int i4 = (blockIdx.x * 256 + threadIdx.x) * 4;
    const int a = i4 & 511, b = i4 >> 17;
    float4 s = *(const float4*)&partial[i4];
#pragma unroll
    for (int kc = 1; kc < 8; ++kc) {
      float4 p = *(const float4*)&partial[((size_t)kc << 20) + i4];
      s.x += p.x; s.y += p.y; s.z += p.z; s.w += p.w;
    }
    const float4 rs = *(const float4*)&rsum[b * 512 + a];
    s.x /= rs.x; s.y /= rs.y; s.z /= rs.z; s.w /= rs.w;
    *(float4*)&ctx[i4] = s;
  } else {
    const int row = blockIdx.x - 1024;
    const float inv = 1.0f / rsum[row];
    const unsigned short* src = attbf + (size_t)row * HW;
    float* dst = attn + (size_t)row * HW;
    const int tid = threadIdx.x;
#pragma unroll
    for (int i = 0; i < 2; ++i) {
      short8 v = *(const short8*)(src + tid * 8 + i * 2048);
      float4 o0, o1;
      o0.x = bf2f((unsigned short)v[0]) * inv;
      o0.y = bf2f((unsigned short)v[1]) * inv;
      o0.z = bf2f((unsigned short)v[2]) * inv;
      o0.w = bf2f((unsigned short)v[3]) * inv;
      o1.x = bf2f((unsigned short)v[4]) * inv;
      o1.y = bf2f((unsigned short)v[5]) * inv;
      o1.z = bf2f((unsigned short)v[6]) * inv;
      o1.w = bf2f((unsigned short)v[7]) * inv;
      *(float4*)(dst + tid * 8 + i * 2048) = o0;
      *(float4*)(dst + tid * 8 + i * 2048 + 4) = o1;
    }
  }
}

// ---------------------------------------------------------------------------
extern "C" void kernel_launch(void* const* d_in, const int* in_sizes, int n_in,
                              void* d_out, int out_size, void* d_ws, size_t ws_size,
                              hipStream_t stream) {
  const float* x     = (const float*)d_in[0];
  const float* Wf    = (const float*)d_in[1];
  const float* bfeat = (const float*)d_in[2];
  const float* Wa    = (const float*)d_in[3];
  const float* ba    = (const float*)d_in[4];
  float* ctx  = (float*)d_out;
  float* attn = ctx + CTX_ELEMS;

  unsigned short* featbf = (unsigned short*)d_ws;                 // 16.8 MB
  unsigned short* attbf  = featbf + (size_t)NB * 256 * HW;        // 33.6 MB
  float* rsum_part = (float*)(attbf + (size_t)4096 * HW);         // 256 KB (16 pblocks)
  float* rsum = rsum_part + 16 * 4096;                            // 16 KB
  float* partial = rsum + 4096;                                   // 33.6 MB (8 x 4 MB)

  k_main<<<1536, 256, 0, stream>>>(x, Wa, Wf, ba, bfeat, attbf, featbf, rsum_part);
  k_ctx<<<dim3(8, 2, 64), 256, 0, stream>>>(featbf, attbf, rsum_part, rsum, partial);
  k_final<<<5120, 256, 0, stream>>>(partial, rsum, attbf, ctx, attn);
}